// Round 13
// baseline (147.572 us; speedup 1.0000x reference)
//
#include <hip/hip_runtime.h>

namespace {

constexpr int Bn = 2;
constexpr int Dn = 64;
constexpr int Hn = 96;
constexpr int Wn = 96;
constexpr int HW = Hn * Wn;          // 9216
constexpr int S  = Dn * HW;          // 589824 per (vol,batch) slab
constexpr int NBS = Bn * S;          // 1179648
constexpr int NT  = 2 * NBS;         // 2359296 (slabs: predB0,predB1,truthB0,truthB1)
constexpr int WPR = Wn / 32;         // 3 words per x-row
constexpr int WPP = HW / 32;         // 288 words per z-plane
constexpr int WPS = S / 32;          // 18432 words per slab
constexpr int NTW = NT / 32;         // 73728 packed words
constexpr float EPSf = 1e-7f;
constexpr int BLK_SUMS = NBS / 4 / 256;   // 1152 (one quad per thread)
#define BIGF 1e12f                   // RN(1e12): exact all-foreground EDT value

// ---- binarize + per-column 64-bit zero-masks (no D2 materialization) ----
__global__ __launch_bounds__(256) void k_bin(const float* __restrict__ logits,
                                             const int* __restrict__ labels,
                                             unsigned* __restrict__ Mb,
                                             unsigned long long* __restrict__ ZM) {
  __shared__ unsigned bits[64];                // one word per z (32 cols)
  __shared__ unsigned zlo[32], zhi[32];
  int slab = blockIdx.x / 288;                 // 1152 blocks = 4 slabs x 288 groups
  int cg = blockIdx.x - slab * 288;            // 32-column group
  int c0 = cg * 32;
  int tid = threadIdx.x;
  int lane = tid & 63;
  for (int t = tid; t < 2048; t += 256) {
    int zz = t >> 5;
    int col = t & 31;
    int s = zz * HW + c0 + col;
    bool v;
    if (slab < 2) {
      float l0 = logits[(slab * 2 + 0) * S + s];
      float l1 = logits[(slab * 2 + 1) * S + s];
      v = l1 > l0;                             // softmax(p1)>0.5 <=> l1>l0
    } else {
      v = labels[(slab - 2) * S + s] > 0;
    }
    unsigned long long m = __ballot(v);
    if (lane == 0) {
      unsigned w = (unsigned)m;
      bits[zz] = w;
      Mb[slab * WPS + zz * WPP + cg] = w;
    } else if (lane == 32) {
      unsigned w = (unsigned)(m >> 32);
      bits[zz] = w;
      Mb[slab * WPS + zz * WPP + cg] = w;
    }
  }
  __syncthreads();
  if (tid < 64) {                              // per-col zero masks
    int col = tid & 31;
    int base = (tid < 32) ? 0 : 32;
    unsigned zw = 0u;
    #pragma unroll
    for (int j = 0; j < 32; ++j)
      zw |= (((bits[base + j] >> col) & 1u) ^ 1u) << j;
    if (tid < 32) zlo[col] = zw; else zhi[col] = zw;
  }
  __syncthreads();
  if (tid < 32)
    ZM[slab * HW + c0 + tid] =
        ((unsigned long long)zhi[tid] << 32) | (unsigned long long)zlo[tid];
}

// ---- fused skeleton + EDT(y,x) + masked pmax, quarter-plane per block ----
// Phase A: R11/R12-verified 11-level skeleton chain (absmax 0 twice).
// Phase B: EDT pass1 with f[j] from R12-verified bit-scan (z-dist^2, bit-exact).
// Phase C: EDT pass2 (g-trick) + masked pmax using the block's OWN skel words
//          from LDS -- no cross-kernel race, D2 never materialized.
__global__ __launch_bounds__(256) void k_skelEDT(const unsigned* __restrict__ x,
                                                 const unsigned long long* __restrict__ ZM,
                                                 unsigned* __restrict__ skel,
                                                 float* __restrict__ EF,
                                                 float* __restrict__ pmax) {
  __shared__ unsigned bufA[3600];              // L0 (25x48x3); reused as Bh floats
  __shared__ unsigned bufB[3174];
  __shared__ unsigned Sbuf[72];
  __shared__ unsigned skbuf[72];
  __shared__ float ldsf[4];
  int slab = blockIdx.x >> 8;                  // 1024 = slab(4) x z(64) x q(4)
  int z = (blockIdx.x >> 2) & 63;
  int y0 = (blockIdx.x & 3) * 24;
  int tid = threadIdx.x;
  const unsigned* xs = x + slab * WPS;
  // ---- Phase A: skeleton ----
  for (int t = tid; t < 25 * 48 * 3; t += 256) {
    int p = t / 144;
    int rem = t - p * 144;
    int r = rem / 3;
    int wx = rem - r * 3;
    int zz = z - 12 + p, yy = y0 - 12 + r;
    bufA[t] = (zz >= 0 && zz < Dn && yy >= 0 && yy < Hn)
                ? xs[zz * WPP + yy * WPR + wx] : 0xFFFFFFFFu;
  }
  __syncthreads();
  unsigned skreg = 0u;                         // valid for tid < 72
  int ro = tid / 3, wxo = tid - ro * 3;
  int yyo = y0 + ro;
  #pragma unroll
  for (int k = 1; k <= 11; ++k) {
    unsigned* src = (k & 1) ? bufA : bufB;     // level k-1
    unsigned* dst = (k & 1) ? bufB : bufA;     // level k
    const int Rs = 50 - 2 * k;
    const int Pd = 25 - 2 * k, Rd = 48 - 2 * k;
    const int ps = Rs * 3;
    for (int t = tid; t < Pd * Rd * 3; t += 256) {
      int p = t / (Rd * 3);
      int rem = t - p * (Rd * 3);
      int r = rem / 3;
      int wx = rem - r * 3;
      int ci = ((p + 1) * Rs + (r + 1)) * 3 + wx;
      unsigned v = src[ci];
      unsigned l = (v << 1) | (wx > 0 ? (src[ci - 1] >> 31) : 1u);
      unsigned rr = (v >> 1) | (wx < 2 ? (src[ci + 1] << 31) : 0x80000000u);
      dst[t] = v & l & rr & src[ci - 3] & src[ci + 3] & src[ci - ps] & src[ci + ps];
    }
    __syncthreads();
    if (tid < 72) {
      const int pc = 12 - k;
      const int rb = ro + 12 - k;
      unsigned s = 0u;
      #pragma unroll
      for (int dz = -1; dz <= 1; ++dz) {
        if (z + dz < 0 || z + dz >= Dn) continue;
        #pragma unroll
        for (int dy = -1; dy <= 1; ++dy) {
          if (yyo + dy < 0 || yyo + dy >= Hn) continue;
          s |= dst[((pc + dz) * Rd + (rb + dy)) * 3 + wxo];
        }
      }
      Sbuf[tid] = s;
    }
    __syncthreads();
    if (tid < 72) {
      unsigned s = Sbuf[tid];
      unsigned pw = (wxo > 0) ? Sbuf[tid - 1] : 0u;
      unsigned nw = (wxo < 2) ? Sbuf[tid + 1] : 0u;
      unsigned acc = s | ((s << 1) | (pw >> 31)) | ((s >> 1) | (nw << 31));
      unsigned prevC = src[((13 - k) * Rs + (ro + 13 - k)) * 3 + wxo];
      skreg |= prevC & ~acc;
    }
    __syncthreads();
  }
  if (tid < 72) {
    skbuf[tid] = skreg;
    skel[slab * WPS + z * WPP + yyo * WPR + wxo] = skreg;
  }
  __syncthreads();                             // bufA free; skbuf published
  // ---- Phase B: EDT pass1 (y), f[j] via bit-scan from ZM ----
  float* Bh = (float*)bufA;                    // 24 x 97 floats (9.3 KB)
  int pb = slab * S + z * HW;
  if (tid < 192) {
    int xx = tid % 96;
    int c = tid / 96;                          // 0..1
    int ybase = y0 + c * 12;
    const unsigned long long* zc = ZM + slab * HW + xx;
    float m2[12];
    #pragma unroll
    for (int s = 0; s < 12; ++s) m2[s] = -2.0f * (float)(ybase + s);
    float best[12];
    #pragma unroll
    for (int s = 0; s < 12; ++s) best[s] = 3.4e38f;
    float jf = 0.0f;
    #pragma unroll 2
    for (int j = 0; j < Hn; ++j) {
      unsigned long long Z = zc[j * 96];
      unsigned long long below = Z & ((2ull << z) - 1ull);
      unsigned long long above = Z >> z;
      float f;
      if (below | above) {
        int ddn = below ? (z - (63 - __builtin_clzll(below))) : 99;
        int dup = above ? __builtin_ctzll(above) : 99;
        int d = ddn < dup ? ddn : dup;
        f = (float)(d * d);
      } else {
        f = BIGF;
      }
      float g = fmaf(jf, jf, f);               // j^2 + f (exact / BIG-absorbed)
      #pragma unroll
      for (int s = 0; s < 12; ++s)
        best[s] = fminf(best[s], fmaf(m2[s], jf, g));
      jf += 1.0f;
    }
    #pragma unroll
    for (int s = 0; s < 12; ++s) {
      float yf = (float)(ybase + s);
      Bh[(c * 12 + s) * 97 + xx] = fmaf(yf, yf, best[s]);
    }
  }
  __syncthreads();
  // ---- Phase C: EDT pass2 (x) + masked pmax from LDS skel words ----
  float m = 0.0f;
  if (tid < 192) {
    int r = tid >> 3;                          // 0..23
    int chunk = tid & 7;                       // 0..7
    int i0 = chunk * 12;
    float m2[12];
    #pragma unroll
    for (int s = 0; s < 12; ++s) m2[s] = -2.0f * (float)(i0 + s);
    float best[12];
    #pragma unroll
    for (int s = 0; s < 12; ++s) best[s] = 3.4e38f;
    float jf = 0.0f;
    #pragma unroll 2
    for (int j = 0; j < Wn; ++j) {
      float f = Bh[r * 97 + j];
      float g = fmaf(jf, jf, f);
      #pragma unroll
      for (int s = 0; s < 12; ++s)
        best[s] = fminf(best[s], fmaf(m2[s], jf, g));
      jf += 1.0f;
    }
    float outv[12];
    #pragma unroll
    for (int s = 0; s < 12; ++s) {
      float xf = (float)(i0 + s);
      outv[s] = fmaf(xf, xf, best[s]);
    }
    int gb = pb + (y0 + r) * 96 + i0;
    ((float4*)(EF + gb))[0] = make_float4(outv[0], outv[1], outv[2], outv[3]);
    ((float4*)(EF + gb))[1] = make_float4(outv[4], outv[5], outv[6], outv[7]);
    ((float4*)(EF + gb))[2] = make_float4(outv[8], outv[9], outv[10], outv[11]);
    int sh = i0 & 31;
    unsigned w0 = skbuf[r * 3 + (i0 >> 5)];
    unsigned w1 = (sh + 11 > 31) ? skbuf[r * 3 + (i0 >> 5) + 1] : 0u;
    unsigned long long wv = ((unsigned long long)w1 << 32) | (unsigned long long)w0;
    unsigned bitsv = (unsigned)(wv >> sh);
    #pragma unroll
    for (int s = 0; s < 12; ++s)
      if ((bitsv >> s) & 1u) m = fmaxf(m, outv[s]);
  }
  #pragma unroll
  for (int o = 32; o > 0; o >>= 1) m = fmaxf(m, __shfl_xor(m, o, 64));
  if ((tid & 63) == 0) ldsf[tid >> 6] = m;
  __syncthreads();
  if (tid == 0)
    pmax[blockIdx.x] = fmaxf(fmaxf(ldsf[0], ldsf[1]), fmaxf(ldsf[2], ldsf[3]));
}

// ---- sums: redundant rmax reduce + per-quad terms -> plain partial stores ----
__global__ __launch_bounds__(256) void k_sums(const float* __restrict__ d2,
                                              const unsigned* __restrict__ skel,
                                              const float* __restrict__ pmax,
                                              double* __restrict__ ps) {
  __shared__ float lmax[4];
  __shared__ double ldsd[4][4];
  int tid = threadIdx.x;
  {
    int wave = tid >> 6, lane = tid & 63;
    const float* pw = pmax + wave * 256;
    float v = fmaxf(fmaxf(pw[lane], pw[lane + 64]),
                    fmaxf(pw[lane + 128], pw[lane + 192]));
    #pragma unroll
    for (int o = 32; o > 0; o >>= 1) v = fmaxf(v, __shfl_xor(v, o, 64));
    if (lane == 0) lmax[wave] = v;
  }
  __syncthreads();
  int q = blockIdx.x * 256 + tid;              // one quad per thread
  int idx0 = q * 4;
  int b = idx0 / S;
  float rmax_p = sqrtf(lmax[b]);
  float rmax_t = sqrtf(lmax[2 + b]);
  float4 dp4 = ((const float4*)d2)[q];
  float4 dt4 = ((const float4*)(d2 + NBS))[q];
  unsigned spw = (skel[idx0 >> 5] >> (idx0 & 31)) & 0xFu;
  unsigned stw = (skel[(NBS + idx0) >> 5] >> (idx0 & 31)) & 0xFu;
  const float* dp = &dp4.x;
  const float* dt = &dt4.x;
  double acc[4] = {0.0, 0.0, 0.0, 0.0};
  #pragma unroll
  for (int s = 0; s < 4; ++s) {
    float dist_p = sqrtf(dp[s]);
    float dist_t = sqrtf(dt[s]);
    bool sp = (spw >> s) & 1u;
    bool st = (stw >> s) & 1u;
    float q_vp = (rmax_p > 0.0f) ? dist_p / rmax_p : dist_p;
    float q_vl = (rmax_t > 0.0f) ? dist_t / rmax_t : dist_t;
    float q_spvp = sp ? q_vp : 0.0f;
    float q_slvl = st ? q_vl : 0.0f;
    float q_sp = sp ? (1.0f + EPSf) / (q_spvp * q_spvp + EPSf) : 0.0f;
    float q_sl = st ? (1.0f + EPSf) / (q_slvl * q_slvl + EPSf) : 0.0f;
    acc[0] += (double)(q_sp * q_vl);
    acc[1] += (double)(((q_spvp != 0.0f) && (q_slvl == 0.0f)) ? q_spvp * q_sp
                                                              : q_slvl * q_sp);
    acc[2] += (double)(q_sl * q_vp);
    acc[3] += (double)(((q_slvl != 0.0f) && (q_spvp == 0.0f)) ? q_slvl * q_sl
                                                              : q_spvp * q_sl);
  }
  #pragma unroll
  for (int k = 0; k < 4; ++k)
    #pragma unroll
    for (int o = 32; o > 0; o >>= 1)
      acc[k] += __shfl_xor(acc[k], o, 64);
  if ((tid & 63) == 0) {
    #pragma unroll
    for (int k = 0; k < 4; ++k) ldsd[tid >> 6][k] = acc[k];
  }
  __syncthreads();
  if (tid == 0) {
    #pragma unroll
    for (int k = 0; k < 4; ++k)
      ps[blockIdx.x * 4 + k] = ldsd[0][k] + ldsd[1][k] + ldsd[2][k] + ldsd[3][k];
  }
}

// ---- final: reduce 1152x4 partials, compute loss (1 block) ----
__global__ __launch_bounds__(256) void k_final(const double* __restrict__ ps,
                                               float* __restrict__ out) {
  __shared__ double ldsd[4][4];
  int tid = threadIdx.x;
  double s[4] = {0.0, 0.0, 0.0, 0.0};
  for (int i = tid; i < BLK_SUMS; i += 256) {
    s[0] += ps[i * 4 + 0];
    s[1] += ps[i * 4 + 1];
    s[2] += ps[i * 4 + 2];
    s[3] += ps[i * 4 + 3];
  }
  #pragma unroll
  for (int k = 0; k < 4; ++k)
    #pragma unroll
    for (int o = 32; o > 0; o >>= 1)
      s[k] += __shfl_xor(s[k], o, 64);
  if ((tid & 63) == 0) {
    #pragma unroll
    for (int k = 0; k < 4; ++k) ldsd[tid >> 6][k] = s[k];
  }
  __syncthreads();
  if (tid == 0) {
    double tot[4];
    #pragma unroll
    for (int k = 0; k < 4; ++k)
      tot[k] = ldsd[0][k] + ldsd[1][k] + ldsd[2][k] + ldsd[3][k];
    double wp = (tot[0] + 1.0) / (tot[1] + 1.0);
    double ws = (tot[2] + 1.0) / (tot[3] + 1.0);
    out[0] = (float)(1.0 - 2.0 * (wp * ws) / (wp + ws));
  }
}

} // namespace

extern "C" void kernel_launch(void* const* d_in, const int* in_sizes, int n_in,
                              void* d_out, int out_size, void* d_ws, size_t ws_size,
                              hipStream_t stream) {
  (void)in_sizes; (void)n_in; (void)out_size; (void)ws_size;
  const float* logits = (const float*)d_in[0];   // [B,2,D,H,W] f32
  const int* labels   = (const int*)d_in[1];     // [B,1,D,H,W] i32
  float* out = (float*)d_out;

  float* EF = (float*)d_ws;                       // final d2 volume
  unsigned long long* ZM = (unsigned long long*)(EF + NT);  // 4*HW u64 (8B-aligned)
  unsigned* MB    = (unsigned*)(ZM + 4 * HW);     // packed masks
  unsigned* SKELB = MB + NTW;
  float* PMAX  = (float*)(SKELB + NTW);           // 1024 per-tile masked d2 maxes
  double* PS   = (double*)(PMAX + 1024);          // 1152x4 doubles (8B-aligned)

  k_bin<<<1152, 256, 0, stream>>>(logits, labels, MB, ZM);
  k_skelEDT<<<1024, 256, 0, stream>>>(MB, ZM, SKELB, EF, PMAX);
  k_sums<<<1152, 256, 0, stream>>>(EF, SKELB, PMAX, PS);
  k_final<<<1, 256, 0, stream>>>(PS, out);
}

// Round 14
// 143.358 us; speedup vs baseline: 1.0294x; 1.0294x over previous
//
#include <hip/hip_runtime.h>

namespace {

constexpr int Bn = 2;
constexpr int Dn = 64;
constexpr int Hn = 96;
constexpr int Wn = 96;
constexpr int HW = Hn * Wn;          // 9216
constexpr int S  = Dn * HW;          // 589824 per (vol,batch) slab
constexpr int NBS = Bn * S;          // 1179648
constexpr int NT  = 2 * NBS;         // 2359296 (slabs: predB0,predB1,truthB0,truthB1)
constexpr int WPP = HW / 32;         // 288 words per z-plane
constexpr int WPS = S / 32;          // 18432 words per slab
constexpr int NTW = NT / 32;         // 73728 packed words
constexpr float EPSf = 1e-7f;
constexpr int BLK_SUMS = NBS / 4 / 256;   // 1152
#define BIGF 1e12f                   // RN(1e12): exact all-foreground EDT value

// ---- K1: binarize + z-EDT (d^2 via bit-scan, R12-verified) + z-L1 (capped) ----
__global__ __launch_bounds__(256) void k_bin0(const float* __restrict__ logits,
                                              const int* __restrict__ labels,
                                              float* __restrict__ D2,
                                              unsigned char* __restrict__ D1z) {
  __shared__ unsigned bits[64];                // one word per z (32 cols)
  __shared__ unsigned zlo[32], zhi[32];
  int slab = blockIdx.x / 288;                 // 1152 blocks = 4 slabs x 288 groups
  int cg = blockIdx.x - slab * 288;
  int c0 = cg * 32;
  int tid = threadIdx.x;
  int lane = tid & 63;
  for (int t = tid; t < 2048; t += 256) {
    int zz = t >> 5;
    int col = t & 31;
    int s = zz * HW + c0 + col;
    bool v;
    if (slab < 2) {
      float l0 = logits[(slab * 2 + 0) * S + s];
      float l1 = logits[(slab * 2 + 1) * S + s];
      v = l1 > l0;                             // softmax(p1)>0.5 <=> l1>l0
    } else {
      v = labels[(slab - 2) * S + s] > 0;
    }
    unsigned long long m = __ballot(v);
    if (lane == 0)       bits[zz] = (unsigned)m;
    else if (lane == 32) bits[zz] = (unsigned)(m >> 32);
  }
  __syncthreads();
  if (tid < 64) {                              // per-col zero masks
    int col = tid & 31;
    int base = (tid < 32) ? 0 : 32;
    unsigned zw = 0u;
    #pragma unroll
    for (int j = 0; j < 32; ++j)
      zw |= (((bits[base + j] >> col) & 1u) ^ 1u) << j;
    if (tid < 32) zlo[col] = zw; else zhi[col] = zw;
  }
  __syncthreads();
  int col = tid & 31;
  int chunk = tid >> 5;
  int i0 = chunk * 8;
  unsigned long long Z = ((unsigned long long)zhi[col] << 32) | (unsigned long long)zlo[col];
  float* o = D2 + slab * S + c0 + col;
  unsigned char* o1 = D1z + slab * S + c0 + col;
  #pragma unroll
  for (int s = 0; s < 8; ++s) {
    int i = i0 + s;
    unsigned long long below = Z & ((2ull << i) - 1ull);
    unsigned long long above = Z >> i;
    float outv;
    int d1v;
    if (below | above) {
      int ddn = below ? (i - (63 - __builtin_clzll(below))) : 99;
      int dup = above ? __builtin_ctzll(above) : 99;
      int d = ddn < dup ? ddn : dup;
      outv = (float)(d * d);
      d1v = d < 13 ? d : 13;
    } else {
      outv = BIGF;
      d1v = 13;
    }
    o[i * HW] = outv;
    o1[i * HW] = (unsigned char)d1v;
  }
}

// ---- K2: fused y+x EDT (R12-verified g-trick) + y+x L1 scans, quarter-plane ----
__global__ __launch_bounds__(192) void k_edtl1(const float* __restrict__ D2,
                                               const unsigned char* __restrict__ D1z,
                                               float* __restrict__ EF,
                                               unsigned char* __restrict__ D1) {
  __shared__ float Bh[24 * 97];                // L2 pass1 quarter, padded
  __shared__ unsigned char L1b[24 * 96];       // L1 pass1 quarter
  int slab = blockIdx.x >> 8;                  // 1024 = slab(4) x z(64) x q(4)
  int z = (blockIdx.x >> 2) & 63;
  int y0 = (blockIdx.x & 3) * 24;
  int tid = threadIdx.x;
  int pb = slab * S + z * HW;
  int xx = tid % 96;
  int c = tid / 96;                            // 0..1
  int ybase = y0 + c * 12;
  // pass1 L2 (bit-exact g-trick, verified R12/R13)
  {
    float m2[12];
    #pragma unroll
    for (int s = 0; s < 12; ++s) m2[s] = -2.0f * (float)(ybase + s);
    float best[12];
    #pragma unroll
    for (int s = 0; s < 12; ++s) best[s] = 3.4e38f;
    float jf = 0.0f;
    #pragma unroll 2
    for (int j = 0; j < Hn; ++j) {
      float f = D2[pb + j * 96 + xx];
      float g = fmaf(jf, jf, f);
      #pragma unroll
      for (int s = 0; s < 12; ++s)
        best[s] = fminf(best[s], fmaf(m2[s], jf, g));
      jf += 1.0f;
    }
    #pragma unroll
    for (int s = 0; s < 12; ++s) {
      float yf = (float)(ybase + s);
      Bh[(c * 12 + s) * 97 + xx] = fmaf(yf, yf, best[s]);
    }
  }
  // pass1 L1: t1[y] = min_j |y-j| + dz1[j] via prefix/suffix scans (exact ints)
  {
    const unsigned char* dzc = D1z + pb + xx;
    int P = 255;
    for (int j = 0; j < ybase; ++j) P = min(P, (int)dzc[j * 96] - j);
    int A[12];
    #pragma unroll
    for (int s = 0; s < 12; ++s) {
      int j = ybase + s;
      P = min(P, (int)dzc[j * 96] - j);
      A[s] = j + P;
    }
    int Sv = 255;
    for (int j = 95; j >= ybase + 12; --j) Sv = min(Sv, (int)dzc[j * 96] + j);
    #pragma unroll
    for (int s = 11; s >= 0; --s) {
      int j = ybase + s;
      Sv = min(Sv, (int)dzc[j * 96] + j);
      int t1 = min(A[s], Sv - j);
      L1b[(c * 12 + s) * 96 + xx] = (unsigned char)(t1 < 13 ? t1 : 13);
    }
  }
  __syncthreads();
  int r = tid >> 3;                            // 0..23
  int chunk = tid & 7;                         // 0..7
  int i0 = chunk * 12;
  // pass2 L2 -> EF (verified)
  {
    float m2[12];
    #pragma unroll
    for (int s = 0; s < 12; ++s) m2[s] = -2.0f * (float)(i0 + s);
    float best[12];
    #pragma unroll
    for (int s = 0; s < 12; ++s) best[s] = 3.4e38f;
    float jf = 0.0f;
    #pragma unroll 2
    for (int j = 0; j < Wn; ++j) {
      float f = Bh[r * 97 + j];
      float g = fmaf(jf, jf, f);
      #pragma unroll
      for (int s = 0; s < 12; ++s)
        best[s] = fminf(best[s], fmaf(m2[s], jf, g));
      jf += 1.0f;
    }
    int gb = pb + (y0 + r) * 96 + i0;
    float outv[12];
    #pragma unroll
    for (int s = 0; s < 12; ++s) {
      float xf = (float)(i0 + s);
      outv[s] = fmaf(xf, xf, best[s]);
    }
    ((float4*)(EF + gb))[0] = make_float4(outv[0], outv[1], outv[2], outv[3]);
    ((float4*)(EF + gb))[1] = make_float4(outv[4], outv[5], outv[6], outv[7]);
    ((float4*)(EF + gb))[2] = make_float4(outv[8], outv[9], outv[10], outv[11]);
  }
  // pass2 L1 -> D1 (capped 12), packed u32 stores
  {
    const unsigned char* row = &L1b[r * 96];
    int P = 255;
    for (int j = 0; j < i0; ++j) P = min(P, (int)row[j] - j);
    int A[12];
    #pragma unroll
    for (int s = 0; s < 12; ++s) {
      int j = i0 + s;
      P = min(P, (int)row[j] - j);
      A[s] = j + P;
    }
    int Sv = 255;
    for (int j = 95; j >= i0 + 12; --j) Sv = min(Sv, (int)row[j] + j);
    unsigned dv[3] = {0u, 0u, 0u};
    #pragma unroll
    for (int s = 11; s >= 0; --s) {
      int j = i0 + s;
      Sv = min(Sv, (int)row[j] + j);
      int d1 = min(A[s], Sv - j);
      d1 = d1 < 12 ? d1 : 12;
      dv[s >> 2] |= ((unsigned)d1) << ((s & 3) * 8);
    }
    unsigned* dst = (unsigned*)(D1 + pb + (y0 + r) * 96 + i0);  // 4-aligned (12|i0)
    dst[0] = dv[0]; dst[1] = dv[1]; dst[2] = dv[2];
  }
}

// ---- K3: skel = [d1 == max3x3x3(d1)] & [1<=d1<=11]  + masked pmax ----
__global__ __launch_bounds__(256) void k_skelmax(const unsigned char* __restrict__ D1,
                                                 const float* __restrict__ EF,
                                                 unsigned* __restrict__ SKELB,
                                                 float* __restrict__ pmax) {
  __shared__ unsigned char zm[26 * 96];        // z-max over {z-1,z,z+1}, rows y0-1..y0+24
  __shared__ unsigned char cen[26 * 96];       // center-plane d1
  __shared__ float ldsf[4];
  int slab = blockIdx.x >> 8;                  // 1024 = slab(4) x z(64) x q(4)
  int z = (blockIdx.x >> 2) & 63;
  int y0 = (blockIdx.x & 3) * 24;
  int tid = threadIdx.x;
  int pb = slab * S + z * HW;
  for (int t = tid; t < 2496; t += 256) {
    int rr = t / 96;
    int x = t - rr * 96;
    int yy = y0 - 1 + rr;
    unsigned char m = 0, cv = 0;
    if (yy >= 0 && yy < Hn) {
      int base = slab * S + yy * 96 + x;
      cv = D1[base + z * HW];
      m = cv;
      if (z > 0) { unsigned char a = D1[base + (z - 1) * HW]; m = m > a ? m : a; }
      if (z < Dn - 1) { unsigned char a = D1[base + (z + 1) * HW]; m = m > a ? m : a; }
    }
    zm[t] = m;
    cen[t] = cv;
  }
  __syncthreads();
  float mm = 0.0f;
  int wbase = slab * WPS + z * WPP + y0 * 3;   // tile's first skel word
  int lane = tid & 63;
  #pragma unroll
  for (int round = 0; round < 9; ++round) {    // 2304 voxels = 9 x 256
    int v = round * 256 + tid;
    int rr = v / 96;                           // tile row 0..23
    int x = v - rr * 96;
    // mx over zm rows rr..rr+2 (zm row 0 = y0-1), cols x-1..x+1 (x OOB skipped)
    int b1 = rr * 96 + x;
    unsigned char mx = zm[b1];
    { unsigned char a = zm[b1 + 96]; mx = mx > a ? mx : a; }
    { unsigned char a = zm[b1 + 192]; mx = mx > a ? mx : a; }
    if (x > 0) {
      unsigned char a0 = zm[b1 - 1], a1 = zm[b1 + 95], a2 = zm[b1 + 191];
      unsigned char a = a0 > a1 ? a0 : a1; a = a > a2 ? a : a2;
      mx = mx > a ? mx : a;
    }
    if (x < Wn - 1) {
      unsigned char a0 = zm[b1 + 1], a1 = zm[b1 + 97], a2 = zm[b1 + 193];
      unsigned char a = a0 > a1 ? a0 : a1; a = a > a2 ? a : a2;
      mx = mx > a ? mx : a;
    }
    unsigned char d1 = cen[b1 + 96];           // center row = rr+1
    bool sk = (d1 == mx) && (d1 >= 1) && (d1 <= 11);
    unsigned long long bal = __ballot(sk);
    if (lane == 0)       SKELB[wbase + (v >> 5)] = (unsigned)bal;
    else if (lane == 32) SKELB[wbase + (v >> 5)] = (unsigned)(bal >> 32);
    if (sk) mm = fmaxf(mm, EF[pb + (y0 + rr) * 96 + x]);
  }
  #pragma unroll
  for (int o = 32; o > 0; o >>= 1) mm = fmaxf(mm, __shfl_xor(mm, o, 64));
  if (lane == 0) ldsf[tid >> 6] = mm;
  __syncthreads();
  if (tid == 0)
    pmax[blockIdx.x] = fmaxf(fmaxf(ldsf[0], ldsf[1]), fmaxf(ldsf[2], ldsf[3]));
}

// ---- K4: sums (R12-verified; plain partial stores) ----
__global__ __launch_bounds__(256) void k_sums(const float* __restrict__ d2,
                                              const unsigned* __restrict__ skel,
                                              const float* __restrict__ pmax,
                                              double* __restrict__ ps) {
  __shared__ float lmax[4];
  __shared__ double ldsd[4][4];
  int tid = threadIdx.x;
  {
    int wave = tid >> 6, lane = tid & 63;
    const float* pw = pmax + wave * 256;
    float v = fmaxf(fmaxf(pw[lane], pw[lane + 64]),
                    fmaxf(pw[lane + 128], pw[lane + 192]));
    #pragma unroll
    for (int o = 32; o > 0; o >>= 1) v = fmaxf(v, __shfl_xor(v, o, 64));
    if (lane == 0) lmax[wave] = v;
  }
  __syncthreads();
  int q = blockIdx.x * 256 + tid;
  int idx0 = q * 4;
  int b = idx0 / S;
  float rmax_p = sqrtf(lmax[b]);
  float rmax_t = sqrtf(lmax[2 + b]);
  float4 dp4 = ((const float4*)d2)[q];
  float4 dt4 = ((const float4*)(d2 + NBS))[q];
  unsigned spw = (skel[idx0 >> 5] >> (idx0 & 31)) & 0xFu;
  unsigned stw = (skel[(NBS + idx0) >> 5] >> (idx0 & 31)) & 0xFu;
  const float* dp = &dp4.x;
  const float* dt = &dt4.x;
  double acc[4] = {0.0, 0.0, 0.0, 0.0};
  #pragma unroll
  for (int s = 0; s < 4; ++s) {
    float dist_p = sqrtf(dp[s]);
    float dist_t = sqrtf(dt[s]);
    bool sp = (spw >> s) & 1u;
    bool st = (stw >> s) & 1u;
    float q_vp = (rmax_p > 0.0f) ? dist_p / rmax_p : dist_p;
    float q_vl = (rmax_t > 0.0f) ? dist_t / rmax_t : dist_t;
    float q_spvp = sp ? q_vp : 0.0f;
    float q_slvl = st ? q_vl : 0.0f;
    float q_sp = sp ? (1.0f + EPSf) / (q_spvp * q_spvp + EPSf) : 0.0f;
    float q_sl = st ? (1.0f + EPSf) / (q_slvl * q_slvl + EPSf) : 0.0f;
    acc[0] += (double)(q_sp * q_vl);
    acc[1] += (double)(((q_spvp != 0.0f) && (q_slvl == 0.0f)) ? q_spvp * q_sp
                                                              : q_slvl * q_sp);
    acc[2] += (double)(q_sl * q_vp);
    acc[3] += (double)(((q_slvl != 0.0f) && (q_spvp == 0.0f)) ? q_slvl * q_sl
                                                              : q_spvp * q_sl);
  }
  #pragma unroll
  for (int k = 0; k < 4; ++k)
    #pragma unroll
    for (int o = 32; o > 0; o >>= 1)
      acc[k] += __shfl_xor(acc[k], o, 64);
  if ((tid & 63) == 0) {
    #pragma unroll
    for (int k = 0; k < 4; ++k) ldsd[tid >> 6][k] = acc[k];
  }
  __syncthreads();
  if (tid == 0) {
    #pragma unroll
    for (int k = 0; k < 4; ++k)
      ps[blockIdx.x * 4 + k] = ldsd[0][k] + ldsd[1][k] + ldsd[2][k] + ldsd[3][k];
  }
}

// ---- K5: final reduce + loss ----
__global__ __launch_bounds__(256) void k_final(const double* __restrict__ ps,
                                               float* __restrict__ out) {
  __shared__ double ldsd[4][4];
  int tid = threadIdx.x;
  double s[4] = {0.0, 0.0, 0.0, 0.0};
  for (int i = tid; i < BLK_SUMS; i += 256) {
    s[0] += ps[i * 4 + 0];
    s[1] += ps[i * 4 + 1];
    s[2] += ps[i * 4 + 2];
    s[3] += ps[i * 4 + 3];
  }
  #pragma unroll
  for (int k = 0; k < 4; ++k)
    #pragma unroll
    for (int o = 32; o > 0; o >>= 1)
      s[k] += __shfl_xor(s[k], o, 64);
  if ((tid & 63) == 0) {
    #pragma unroll
    for (int k = 0; k < 4; ++k) ldsd[tid >> 6][k] = s[k];
  }
  __syncthreads();
  if (tid == 0) {
    double tot[4];
    #pragma unroll
    for (int k = 0; k < 4; ++k)
      tot[k] = ldsd[0][k] + ldsd[1][k] + ldsd[2][k] + ldsd[3][k];
    double wp = (tot[0] + 1.0) / (tot[1] + 1.0);
    double ws = (tot[2] + 1.0) / (tot[3] + 1.0);
    out[0] = (float)(1.0 - 2.0 * (wp * ws) / (wp + ws));
  }
}

} // namespace

extern "C" void kernel_launch(void* const* d_in, const int* in_sizes, int n_in,
                              void* d_out, int out_size, void* d_ws, size_t ws_size,
                              hipStream_t stream) {
  (void)in_sizes; (void)n_in; (void)out_size; (void)ws_size;
  const float* logits = (const float*)d_in[0];   // [B,2,D,H,W] f32
  const int* labels   = (const int*)d_in[1];     // [B,1,D,H,W] i32
  float* out = (float*)d_out;

  float* EF = (float*)d_ws;                       // final Euclidean d2
  float* D2 = EF + NT;                            // z-pass d2
  unsigned char* D1z = (unsigned char*)(D2 + NT); // z-pass L1 (capped 13)
  unsigned char* D1  = D1z + NT;                  // full L1 DT (capped 12)
  unsigned* SKELB = (unsigned*)(D1 + NT);
  float* PMAX  = (float*)(SKELB + NTW);           // 1024 per-tile masked maxes
  double* PS   = (double*)(PMAX + 1024);          // 1152x4 doubles (8B-aligned)

  k_bin0<<<1152, 256, 0, stream>>>(logits, labels, D2, D1z);
  k_edtl1<<<1024, 192, 0, stream>>>(D2, D1z, EF, D1);
  k_skelmax<<<1024, 256, 0, stream>>>(D1, EF, SKELB, PMAX);
  k_sums<<<1152, 256, 0, stream>>>(EF, SKELB, PMAX, PS);
  k_final<<<1, 256, 0, stream>>>(PS, out);
}

// Round 15
// 118.550 us; speedup vs baseline: 1.2448x; 1.2093x over previous
//
#include <hip/hip_runtime.h>

namespace {

constexpr int Bn = 2;
constexpr int Dn = 64;
constexpr int Hn = 96;
constexpr int Wn = 96;
constexpr int HW = Hn * Wn;          // 9216
constexpr int S  = Dn * HW;          // 589824 per (vol,batch) slab
constexpr int NBS = Bn * S;          // 1179648
constexpr int NT  = 2 * NBS;         // 2359296 (slabs: predB0,predB1,truthB0,truthB1)
constexpr int WPP = HW / 32;         // 288 words per z-plane
constexpr int WPS = S / 32;          // 18432 words per slab
constexpr int NTW = NT / 32;         // 73728 packed words
constexpr float EPSf = 1e-7f;
constexpr int BLK_SUMS = NBS / 4 / 256;   // 1152
#define BIGF 1e12f                   // RN(1e12): exact all-foreground EDT value
constexpr int LINF = 1 << 20;

// ---- K1: binarize + z-EDT: d^2 as u16 (0xFFFF=BIG) + z-L1 u8 (255=inf) ----
__global__ __launch_bounds__(256) void k_bin0(const float* __restrict__ logits,
                                              const int* __restrict__ labels,
                                              unsigned short* __restrict__ FZ,
                                              unsigned char* __restrict__ DZ) {
  __shared__ unsigned bits[64];
  __shared__ unsigned zlo[32], zhi[32];
  int slab = blockIdx.x / 288;                 // 1152 blocks = 4 slabs x 288 groups
  int cg = blockIdx.x - slab * 288;
  int c0 = cg * 32;
  int tid = threadIdx.x;
  int lane = tid & 63;
  for (int t = tid; t < 2048; t += 256) {
    int zz = t >> 5;
    int col = t & 31;
    int s = zz * HW + c0 + col;
    bool v;
    if (slab < 2) {
      float l0 = logits[(slab * 2 + 0) * S + s];
      float l1 = logits[(slab * 2 + 1) * S + s];
      v = l1 > l0;                             // softmax(p1)>0.5 <=> l1>l0
    } else {
      v = labels[(slab - 2) * S + s] > 0;
    }
    unsigned long long m = __ballot(v);
    if (lane == 0)       bits[zz] = (unsigned)m;
    else if (lane == 32) bits[zz] = (unsigned)(m >> 32);
  }
  __syncthreads();
  if (tid < 64) {
    int col = tid & 31;
    int base = (tid < 32) ? 0 : 32;
    unsigned zw = 0u;
    #pragma unroll
    for (int j = 0; j < 32; ++j)
      zw |= (((bits[base + j] >> col) & 1u) ^ 1u) << j;
    if (tid < 32) zlo[col] = zw; else zhi[col] = zw;
  }
  __syncthreads();
  int col = tid & 31;
  int chunk = tid >> 5;
  int i0 = chunk * 8;
  unsigned long long Z = ((unsigned long long)zhi[col] << 32) | (unsigned long long)zlo[col];
  unsigned short* o = FZ + slab * S + c0 + col;
  unsigned char* o1 = DZ + slab * S + c0 + col;
  #pragma unroll
  for (int s = 0; s < 8; ++s) {
    int i = i0 + s;
    unsigned long long below = Z & ((2ull << i) - 1ull);
    unsigned long long above = Z >> i;
    unsigned short fv;
    unsigned char dv;
    if (below | above) {
      int ddn = below ? (i - (63 - __builtin_clzll(below))) : 99;
      int dup = above ? __builtin_ctzll(above) : 99;
      int d = ddn < dup ? ddn : dup;           // <= 63
      fv = (unsigned short)(d * d);
      dv = (unsigned char)d;
    } else {
      fv = 0xFFFFu;
      dv = 255;
    }
    o[i * HW] = fv;
    o1[i * HW] = dv;
  }
}

// ---- K2: windowed exact EDT (y,x) + L1 scans, quarter-plane per block ----
// Window bound: Euclid <= L1, so only |i-j| <= L1bound candidates can win;
// all small candidates are exact ints -> integer min == reference float min.
__global__ __launch_bounds__(256) void k_edtl1(const unsigned short* __restrict__ FZ,
                                               const unsigned char* __restrict__ DZ,
                                               float* __restrict__ EF,
                                               unsigned char* __restrict__ D1) {
  __shared__ __align__(16) unsigned shm[8640]; // 34560 B
  unsigned short* fz = (unsigned short*)shm;          // 9216 u16 (plane d2z)
  unsigned char*  dz = (unsigned char*)(shm + 4608);  // 9216 u8  (plane L1z)
  unsigned char*  t1 = (unsigned char*)(shm + 6912);  // 24x96 u8 (zy-L1, tile)
  unsigned short* o1 = (unsigned short*)(shm + 7488); // 24x96 u16 (pass1 out)
  unsigned short* Afwd = (unsigned short*)shm;        // reuse fz after pass1
  unsigned short* Bbwd = (unsigned short*)(shm + 4608); // reuse dz after t1
  int slab = blockIdx.x >> 8;                  // 1024 = slab(4) x z(64) x q(4)
  int z = (blockIdx.x >> 2) & 63;
  int y0 = (blockIdx.x & 3) * 24;
  int tid = threadIdx.x;
  int pb = slab * S + z * HW;
  // stage plane (u16 d2z + u8 L1z), fully coalesced
  {
    const uint4* s4 = (const uint4*)(FZ + pb);
    uint4* d4 = (uint4*)fz;
    for (int t = tid; t < 1152; t += 256) d4[t] = s4[t];
    const uint4* s2 = (const uint4*)(DZ + pb);
    uint4* d2 = (uint4*)(shm + 4608);
    for (int t = tid; t < 576; t += 256) d2[t] = s2[t];
  }
  __syncthreads();
  // t1[rr][xx] = min_j |y-j| + dz[j][xx]  (uncapped; 255 = inf), tile rows only
  if (tid < 96) {
    int xx = tid;
    int P = LINF;
    int A[24];
    for (int j = 0; j < y0; ++j) {
      int v = dz[j * 96 + xx]; if (v == 255) v = LINF;
      P = min(P, v - j);
    }
    #pragma unroll
    for (int s = 0; s < 24; ++s) {
      int j = y0 + s;
      int v = dz[j * 96 + xx]; if (v == 255) v = LINF;
      P = min(P, v - j);
      A[s] = j + P;
    }
    int Sv = LINF;
    for (int j = 95; j >= y0 + 24; --j) {
      int v = dz[j * 96 + xx]; if (v == 255) v = LINF;
      Sv = min(Sv, v + j);
    }
    #pragma unroll
    for (int s = 23; s >= 0; --s) {
      int j = y0 + s;
      int v = dz[j * 96 + xx]; if (v == 255) v = LINF;
      Sv = min(Sv, v + j);
      int t = min(A[s], Sv - j);               // finite <= 158
      t1[s * 96 + xx] = (unsigned char)(t > 254 ? 255 : t);
    }
  }
  __syncthreads();
  // pass1 windowed: out1[y][xx] = min_{|y-j|<=t1} (y-j)^2 + fz[j][xx]
  for (int v = tid; v < 2304; v += 256) {
    int rr = v / 96;
    int xx = v - rr * 96;
    int y = y0 + rr;
    int r = t1[rr * 96 + xx];
    unsigned short res;
    if (r == 255) {
      res = 0xFFFFu;                           // whole (y,z) slice BIG -> RN(1e12)
    } else {
      int lo = y - r; if (lo < 0) lo = 0;
      int hi = y + r; if (hi > 95) hi = 95;
      int best = 1 << 30;
      for (int j = lo; j <= hi; ++j) {
        unsigned short f = fz[j * 96 + xx];
        if (f != 0xFFFFu) {
          int dd = y - j;
          best = min(best, dd * dd + (int)f);
        }
      }
      res = (unsigned short)best;              // <= t1^2 <= 24964; argmin in window
    }
    o1[rr * 96 + xx] = res;
  }
  __syncthreads();                             // fz free now
  // d1 row scans: Afwd/Bbwd halves of d1[rr][x] = min_j |x-j| + t1[rr][j]
  if (tid < 24) {                              // forward (wave 0)
    int rr = tid;
    int P = LINF;
    for (int j = 0; j < 96; ++j) {
      int v = t1[rr * 96 + j]; if (v == 255) v = LINF;
      P = min(P, v - j);
      int a = j + P;
      Afwd[rr * 96 + j] = (unsigned short)(a > 60000 ? 60000 : a);
    }
  }
  if (tid >= 64 && tid < 88) {                 // backward (wave 1)
    int rr = tid - 64;
    int Sv = LINF;
    for (int j = 95; j >= 0; --j) {
      int v = t1[rr * 96 + j]; if (v == 255) v = LINF;
      Sv = min(Sv, v + j);
      int b = Sv - j;                          // >= 0
      Bbwd[rr * 96 + j] = (unsigned short)(b > 60000 ? 60000 : b);
    }
  }
  __syncthreads();
  // pass2 windowed: EF + capped-12 D1
  for (int v = tid; v < 2304; v += 256) {
    int rr = v / 96;
    int x = v - rr * 96;
    int d1v = min((int)Afwd[rr * 96 + x], (int)Bbwd[rr * 96 + x]);
    float outf;
    int d1c;
    if (d1v > 253) {                           // inf: whole plane BIG
      outf = BIGF;
      d1c = 12;
    } else {
      d1c = d1v < 12 ? d1v : 12;
      int lo = x - d1v; if (lo < 0) lo = 0;
      int hi = x + d1v; if (hi > 95) hi = 95;
      int best = 1 << 30;
      for (int j = lo; j <= hi; ++j) {
        unsigned short f = o1[rr * 96 + j];
        if (f != 0xFFFFu) {
          int dd = x - j;
          best = min(best, dd * dd + (int)f);
        }
      }
      outf = (float)best;                      // <= d1^2 <= 64009, exact in f32
    }
    int gb = pb + (y0 + rr) * 96 + x;
    EF[gb] = outf;
    D1[gb] = (unsigned char)d1c;
  }
}

// ---- K3: skel = [d1 == max3x3x3(d1)] & [1<=d1<=11] + masked pmax (R14-verified) ----
__global__ __launch_bounds__(256) void k_skelmax(const unsigned char* __restrict__ D1,
                                                 const float* __restrict__ EF,
                                                 unsigned* __restrict__ SKELB,
                                                 float* __restrict__ pmax) {
  __shared__ unsigned char zm[26 * 96];
  __shared__ unsigned char cen[26 * 96];
  __shared__ float ldsf[4];
  int slab = blockIdx.x >> 8;
  int z = (blockIdx.x >> 2) & 63;
  int y0 = (blockIdx.x & 3) * 24;
  int tid = threadIdx.x;
  int pb = slab * S + z * HW;
  for (int t = tid; t < 2496; t += 256) {
    int rr = t / 96;
    int x = t - rr * 96;
    int yy = y0 - 1 + rr;
    unsigned char m = 0, cv = 0;
    if (yy >= 0 && yy < Hn) {
      int base = slab * S + yy * 96 + x;
      cv = D1[base + z * HW];
      m = cv;
      if (z > 0) { unsigned char a = D1[base + (z - 1) * HW]; m = m > a ? m : a; }
      if (z < Dn - 1) { unsigned char a = D1[base + (z + 1) * HW]; m = m > a ? m : a; }
    }
    zm[t] = m;
    cen[t] = cv;
  }
  __syncthreads();
  float mm = 0.0f;
  int wbase = slab * WPS + z * WPP + y0 * 3;
  int lane = tid & 63;
  #pragma unroll
  for (int round = 0; round < 9; ++round) {
    int v = round * 256 + tid;
    int rr = v / 96;
    int x = v - rr * 96;
    int b1 = rr * 96 + x;
    unsigned char mx = zm[b1];
    { unsigned char a = zm[b1 + 96]; mx = mx > a ? mx : a; }
    { unsigned char a = zm[b1 + 192]; mx = mx > a ? mx : a; }
    if (x > 0) {
      unsigned char a0 = zm[b1 - 1], a1 = zm[b1 + 95], a2 = zm[b1 + 191];
      unsigned char a = a0 > a1 ? a0 : a1; a = a > a2 ? a : a2;
      mx = mx > a ? mx : a;
    }
    if (x < Wn - 1) {
      unsigned char a0 = zm[b1 + 1], a1 = zm[b1 + 97], a2 = zm[b1 + 193];
      unsigned char a = a0 > a1 ? a0 : a1; a = a > a2 ? a : a2;
      mx = mx > a ? mx : a;
    }
    unsigned char d1 = cen[b1 + 96];
    bool sk = (d1 == mx) && (d1 >= 1) && (d1 <= 11);
    unsigned long long bal = __ballot(sk);
    if (lane == 0)       SKELB[wbase + (v >> 5)] = (unsigned)bal;
    else if (lane == 32) SKELB[wbase + (v >> 5)] = (unsigned)(bal >> 32);
    if (sk) mm = fmaxf(mm, EF[pb + (y0 + rr) * 96 + x]);
  }
  #pragma unroll
  for (int o = 32; o > 0; o >>= 1) mm = fmaxf(mm, __shfl_xor(mm, o, 64));
  if (lane == 0) ldsf[tid >> 6] = mm;
  __syncthreads();
  if (tid == 0)
    pmax[blockIdx.x] = fmaxf(fmaxf(ldsf[0], ldsf[1]), fmaxf(ldsf[2], ldsf[3]));
}

// ---- K4: sums (R12-verified; plain partial stores) ----
__global__ __launch_bounds__(256) void k_sums(const float* __restrict__ d2,
                                              const unsigned* __restrict__ skel,
                                              const float* __restrict__ pmax,
                                              double* __restrict__ ps) {
  __shared__ float lmax[4];
  __shared__ double ldsd[4][4];
  int tid = threadIdx.x;
  {
    int wave = tid >> 6, lane = tid & 63;
    const float* pw = pmax + wave * 256;
    float v = fmaxf(fmaxf(pw[lane], pw[lane + 64]),
                    fmaxf(pw[lane + 128], pw[lane + 192]));
    #pragma unroll
    for (int o = 32; o > 0; o >>= 1) v = fmaxf(v, __shfl_xor(v, o, 64));
    if (lane == 0) lmax[wave] = v;
  }
  __syncthreads();
  int q = blockIdx.x * 256 + tid;
  int idx0 = q * 4;
  int b = idx0 / S;
  float rmax_p = sqrtf(lmax[b]);
  float rmax_t = sqrtf(lmax[2 + b]);
  float4 dp4 = ((const float4*)d2)[q];
  float4 dt4 = ((const float4*)(d2 + NBS))[q];
  unsigned spw = (skel[idx0 >> 5] >> (idx0 & 31)) & 0xFu;
  unsigned stw = (skel[(NBS + idx0) >> 5] >> (idx0 & 31)) & 0xFu;
  const float* dp = &dp4.x;
  const float* dt = &dt4.x;
  double acc[4] = {0.0, 0.0, 0.0, 0.0};
  #pragma unroll
  for (int s = 0; s < 4; ++s) {
    float dist_p = sqrtf(dp[s]);
    float dist_t = sqrtf(dt[s]);
    bool sp = (spw >> s) & 1u;
    bool st = (stw >> s) & 1u;
    float q_vp = (rmax_p > 0.0f) ? dist_p / rmax_p : dist_p;
    float q_vl = (rmax_t > 0.0f) ? dist_t / rmax_t : dist_t;
    float q_spvp = sp ? q_vp : 0.0f;
    float q_slvl = st ? q_vl : 0.0f;
    float q_sp = sp ? (1.0f + EPSf) / (q_spvp * q_spvp + EPSf) : 0.0f;
    float q_sl = st ? (1.0f + EPSf) / (q_slvl * q_slvl + EPSf) : 0.0f;
    acc[0] += (double)(q_sp * q_vl);
    acc[1] += (double)(((q_spvp != 0.0f) && (q_slvl == 0.0f)) ? q_spvp * q_sp
                                                              : q_slvl * q_sp);
    acc[2] += (double)(q_sl * q_vp);
    acc[3] += (double)(((q_slvl != 0.0f) && (q_spvp == 0.0f)) ? q_slvl * q_sl
                                                              : q_spvp * q_sl);
  }
  #pragma unroll
  for (int k = 0; k < 4; ++k)
    #pragma unroll
    for (int o = 32; o > 0; o >>= 1)
      acc[k] += __shfl_xor(acc[k], o, 64);
  if ((tid & 63) == 0) {
    #pragma unroll
    for (int k = 0; k < 4; ++k) ldsd[tid >> 6][k] = acc[k];
  }
  __syncthreads();
  if (tid == 0) {
    #pragma unroll
    for (int k = 0; k < 4; ++k)
      ps[blockIdx.x * 4 + k] = ldsd[0][k] + ldsd[1][k] + ldsd[2][k] + ldsd[3][k];
  }
}

// ---- K5: final reduce + loss ----
__global__ __launch_bounds__(256) void k_final(const double* __restrict__ ps,
                                               float* __restrict__ out) {
  __shared__ double ldsd[4][4];
  int tid = threadIdx.x;
  double s[4] = {0.0, 0.0, 0.0, 0.0};
  for (int i = tid; i < BLK_SUMS; i += 256) {
    s[0] += ps[i * 4 + 0];
    s[1] += ps[i * 4 + 1];
    s[2] += ps[i * 4 + 2];
    s[3] += ps[i * 4 + 3];
  }
  #pragma unroll
  for (int k = 0; k < 4; ++k)
    #pragma unroll
    for (int o = 32; o > 0; o >>= 1)
      s[k] += __shfl_xor(s[k], o, 64);
  if ((tid & 63) == 0) {
    #pragma unroll
    for (int k = 0; k < 4; ++k) ldsd[tid >> 6][k] = s[k];
  }
  __syncthreads();
  if (tid == 0) {
    double tot[4];
    #pragma unroll
    for (int k = 0; k < 4; ++k)
      tot[k] = ldsd[0][k] + ldsd[1][k] + ldsd[2][k] + ldsd[3][k];
    double wp = (tot[0] + 1.0) / (tot[1] + 1.0);
    double ws = (tot[2] + 1.0) / (tot[3] + 1.0);
    out[0] = (float)(1.0 - 2.0 * (wp * ws) / (wp + ws));
  }
}

} // namespace

extern "C" void kernel_launch(void* const* d_in, const int* in_sizes, int n_in,
                              void* d_out, int out_size, void* d_ws, size_t ws_size,
                              hipStream_t stream) {
  (void)in_sizes; (void)n_in; (void)out_size; (void)ws_size;
  const float* logits = (const float*)d_in[0];   // [B,2,D,H,W] f32
  const int* labels   = (const int*)d_in[1];     // [B,1,D,H,W] i32
  float* out = (float*)d_out;

  float* EF = (float*)d_ws;                        // final Euclidean d2 (f32)
  unsigned short* FZ = (unsigned short*)(EF + NT); // z-pass d2 (u16)
  unsigned char* DZ  = (unsigned char*)(FZ + NT);  // z-pass L1 (u8, 255=inf)
  unsigned char* D1  = DZ + NT;                    // 3D L1, capped 12 (u8)
  unsigned* SKELB = (unsigned*)(D1 + NT);
  float* PMAX  = (float*)(SKELB + NTW);            // 1024 per-tile masked maxes
  double* PS   = (double*)(PMAX + 1024);           // 1152x4 doubles (8B-aligned)

  k_bin0<<<1152, 256, 0, stream>>>(logits, labels, FZ, DZ);
  k_edtl1<<<1024, 256, 0, stream>>>(FZ, DZ, EF, D1);
  k_skelmax<<<1024, 256, 0, stream>>>(D1, EF, SKELB, PMAX);
  k_sums<<<1152, 256, 0, stream>>>(EF, SKELB, PMAX, PS);
  k_final<<<1, 256, 0, stream>>>(PS, out);
}